// Round 1
// baseline (10576.727 us; speedup 1.0000x reference)
//
#include <hip/hip_runtime.h>

// RNN: out[n,t,:] = tanh(x[n,t,:]@Wx + b + h_{t-1}@Wh),  h_{-1} = h0
// N=64, T=512, D=512, H=1024, fp32 in/out.
// Strategy: split-bf16 (hi/lo) MFMA for both GEMMs; 4 independent batch
// groups x 64 WGs; per-group spin barrier per timestep; Wh in registers.

#define NN 64
#define TT 512
#define DD 512
#define HH 1024

typedef unsigned int  u32;
typedef unsigned short u16;

typedef __attribute__((ext_vector_type(8))) short bf16x8;
typedef __attribute__((ext_vector_type(4))) float f32x4;

#define MFMA16(a, b, c) __builtin_amdgcn_mfma_f32_16x16x32_bf16((a), (b), (c), 0, 0, 0)

__device__ __forceinline__ u32 bf16r(float f) {          // RTNE fp32->bf16 (bits)
    u32 u = __float_as_uint(f);
    return (u + 0x7fffu + ((u >> 16) & 1u)) >> 16;
}
__device__ __forceinline__ float bf16tof(u32 h) { return __uint_as_float(h << 16); }
__device__ __forceinline__ void split2(float f, u32& hi, u32& lo) {
    hi = bf16r(f);
    lo = bf16r(f - bf16tof(hi));
}

// ---------------------------------------------------------------------------
// Prep: pack Wx and Wh into MFMA-fragment order (hi/lo bf16), split h0.
// Fragment layout for 16x16x32: elem index p = ((jt*KB + kb)*64 + lane)*8 + e
//   j = jt*16 + (lane&15),  k = kb*32 + (lane>>4)*8 + e
// ---------------------------------------------------------------------------
__global__ __launch_bounds__(256) void prep_kernel(
    const float* __restrict__ Wx, const float* __restrict__ Wh,
    const float* __restrict__ h0,
    u16* __restrict__ WxPh, u16* __restrict__ WxPl,
    u16* __restrict__ WhPh, u16* __restrict__ WhPl,
    u16* __restrict__ h0h,  u16* __restrict__ h0l)
{
    const int stride = gridDim.x * 256;
    const int gid = blockIdx.x * 256 + threadIdx.x;

    // Wx: 64 jt x 16 kb x 64 lanes x 8 e = 524288
    for (int p = gid; p < 64 * 16 * 64 * 8; p += stride) {
        int e = p & 7, l = (p >> 3) & 63, kb = (p >> 9) & 15, jt = p >> 13;
        int j = jt * 16 + (l & 15);
        int k = kb * 32 + ((l >> 4) << 3) + e;
        u32 hi, lo; split2(Wx[k * HH + j], hi, lo);
        WxPh[p] = (u16)hi; WxPl[p] = (u16)lo;
    }
    // Wh: 64 jt x 32 kb x 64 lanes x 8 e = 1048576
    for (int p = gid; p < 64 * 32 * 64 * 8; p += stride) {
        int e = p & 7, l = (p >> 3) & 63, kb = (p >> 9) & 31, jt = p >> 14;
        int j = jt * 16 + (l & 15);
        int k = kb * 32 + ((l >> 4) << 3) + e;
        u32 hi, lo; split2(Wh[k * HH + j], hi, lo);
        WhPh[p] = (u16)hi; WhPl[p] = (u16)lo;
    }
    // h0 split -> h buffer parity 0
    for (int p = gid; p < NN * HH; p += stride) {
        u32 hi, lo; split2(h0[p], hi, lo);
        h0h[p] = (u16)hi; h0l[p] = (u16)lo;
    }
}

// ---------------------------------------------------------------------------
// Group barrier: 64 blocks, sense-free generation counter, agent scope.
// ---------------------------------------------------------------------------
__device__ __forceinline__ void group_barrier(u32* cnt, u32* gen, u32 nb) {
    __syncthreads();
    if (threadIdx.x == 0) {
        u32 g0 = __hip_atomic_load(gen, __ATOMIC_RELAXED, __HIP_MEMORY_SCOPE_AGENT);
        __threadfence();  // release this block's global writes (agent scope)
        u32 a = __hip_atomic_fetch_add(cnt, 1u, __ATOMIC_ACQ_REL, __HIP_MEMORY_SCOPE_AGENT);
        if (a == nb - 1u) {
            __hip_atomic_store(cnt, 0u, __ATOMIC_RELAXED, __HIP_MEMORY_SCOPE_AGENT);
            __hip_atomic_fetch_add(gen, 1u, __ATOMIC_RELEASE, __HIP_MEMORY_SCOPE_AGENT);
        } else {
            while (__hip_atomic_load(gen, __ATOMIC_RELAXED, __HIP_MEMORY_SCOPE_AGENT) == g0) {
                __builtin_amdgcn_s_sleep(1);
            }
        }
        __builtin_amdgcn_fence(__ATOMIC_ACQUIRE, "agent");
    }
    __syncthreads();
}

// ---------------------------------------------------------------------------
// Main persistent kernel: phase 1 (xw into out) -> group barrier -> scan.
// Grid = 256 blocks x 256 threads. Group g = bid>>6 owns n in [16g,16g+16).
// ---------------------------------------------------------------------------
__global__ __launch_bounds__(256, 1) void rnn_kernel(
    const float* __restrict__ x, const float* __restrict__ b,
    const u16* __restrict__ WxPh, const u16* __restrict__ WxPl,
    const u16* __restrict__ WhPh, const u16* __restrict__ WhPl,
    u16* __restrict__ hb,            // [2 parity][2 hi/lo][64][1024]
    float* __restrict__ out, u32* __restrict__ bar)
{
    __shared__ __align__(16) u32 ldsA[2][128][20];   // hi/lo x 128 rows x 32 bf16 (pad->40)
    __shared__ float ldsRed[4][256];                 // cross-wave K reduction

    const int tid = threadIdx.x;
    const int bid = blockIdx.x;
    const int g   = bid >> 6;       // batch group 0..3
    const int wid = bid & 63;       // WG within group (= j-tile in phase 2)
    const int w   = tid >> 6;       // wave 0..3
    const int l   = tid & 63;       // lane

    u32* cnt = bar + g * 64;
    u32* gen = bar + g * 64 + 32;

    // ======================= Phase 1: out = x@Wx + b =======================
    const int wm = w >> 1, wj = w & 1;   // wave tile 64x64 inside 128x128
    for (int tt = wid; tt < 512; tt += 64) {
        const int mt = tt >> 3, jb = tt & 7;
        const int n  = g * 16 + (mt >> 2);
        const int m0 = (n << 9) + (mt & 3) * 128;     // row in [0,32768)
        const int j0 = jb * 128;

        f32x4 acc[4][4] = {};
        for (int ks = 0; ks < 16; ++ks) {
            const int k0 = ks * 32;
            // stage x tile 128x32 -> split bf16 hi/lo in LDS
            #pragma unroll
            for (int it = 0; it < 8; ++it) {
                int idx = it * 256 + tid;
                int m = idx >> 4, kp = idx & 15;
                float2 v = *(const float2*)(x + (m0 + m) * DD + k0 + kp * 2);
                u32 h0b, l0b, h1b, l1b;
                split2(v.x, h0b, l0b);
                split2(v.y, h1b, l1b);
                ldsA[0][m][kp] = h0b | (h1b << 16);
                ldsA[1][m][kp] = l0b | (l1b << 16);
            }
            __syncthreads();

            bf16x8 afh[4], afl[4], bfh[4], bfl[4];
            #pragma unroll
            for (int mt4 = 0; mt4 < 4; ++mt4) {
                int row = wm * 64 + mt4 * 16 + (l & 15);
                int co  = (l >> 4) * 4;               // uint offset (8 bf16 = 4 uints)
                afh[mt4] = *(const bf16x8*)&ldsA[0][row][co];
                afl[mt4] = *(const bf16x8*)&ldsA[1][row][co];
            }
            #pragma unroll
            for (int jt4 = 0; jt4 < 4; ++jt4) {
                int jtile = jb * 8 + wj * 4 + jt4;
                int off = ((jtile * 16 + ks) * 64 + l) * 8;
                bfh[jt4] = *(const bf16x8*)(WxPh + off);
                bfl[jt4] = *(const bf16x8*)(WxPl + off);
            }
            #pragma unroll
            for (int mt4 = 0; mt4 < 4; ++mt4)
                #pragma unroll
                for (int jt4 = 0; jt4 < 4; ++jt4) {
                    acc[mt4][jt4] = MFMA16(afh[mt4], bfh[jt4], acc[mt4][jt4]);
                    acc[mt4][jt4] = MFMA16(afh[mt4], bfl[jt4], acc[mt4][jt4]);
                    acc[mt4][jt4] = MFMA16(afl[mt4], bfh[jt4], acc[mt4][jt4]);
                }
            __syncthreads();
        }
        // epilogue: += bias, store xw
        #pragma unroll
        for (int jt4 = 0; jt4 < 4; ++jt4) {
            int j = j0 + wj * 64 + jt4 * 16 + (l & 15);
            float bj = b[j];
            #pragma unroll
            for (int mt4 = 0; mt4 < 4; ++mt4)
                #pragma unroll
                for (int r = 0; r < 4; ++r) {
                    int m = m0 + wm * 64 + mt4 * 16 + (l >> 4) * 4 + r;
                    out[m * HH + j] = acc[mt4][jt4][r] + bj;
                }
        }
    }

    // ============== load this wave's Wh fragments into registers ==========
    // WG wid owns j in [wid*16, wid*16+16); wave w owns k in [w*256, w*256+256)
    bf16x8 Bh[8], Bl[8];
    #pragma unroll
    for (int i = 0; i < 8; ++i) {
        int off = ((wid * 32 + w * 8 + i) * 64 + l) * 8;
        Bh[i] = *(const bf16x8*)(WhPh + off);
        Bl[i] = *(const bf16x8*)(WhPl + off);
    }

    group_barrier(cnt, gen, 64);   // xw (this group's rows) fully written

    // ======================= Phase 2: sequential scan ======================
    const int row16 = tid >> 4, col16 = tid & 15;
    const int nA = g * 16 + (l & 15);      // batch row this lane's A-frag covers
    const int nE = g * 16 + row16;         // batch row this thread finalizes
    const int jE = wid * 16 + col16;
    const int kbase = w * 256 + (l >> 4) * 8;

    for (int t = 0; t < TT; ++t) {
        const int par = t & 1;
        const u16* hhi = hb + par * 2 * NN * HH;
        const u16* hlo = hhi + NN * HH;
        u16* nhi = hb + (par ^ 1) * 2 * NN * HH;
        u16* nlo = nhi + NN * HH;

        bf16x8 Ah[8], Al[8];
        #pragma unroll
        for (int i = 0; i < 8; ++i) {
            int off = nA * HH + kbase + i * 32;
            Ah[i] = *(const bf16x8*)(hhi + off);
            Al[i] = *(const bf16x8*)(hlo + off);
        }
        f32x4 ahh = {}, ahl = {}, alh = {};   // 3 independent chains
        #pragma unroll
        for (int i = 0; i < 8; ++i) {
            ahh = MFMA16(Ah[i], Bh[i], ahh);
            ahl = MFMA16(Ah[i], Bl[i], ahl);
            alh = MFMA16(Al[i], Bh[i], alh);
        }
        f32x4 s4 = ahh + ahl + alh;

        // cross-wave K reduction via LDS
        {
            int rbase = (l >> 4) * 4, colW = l & 15;
            #pragma unroll
            for (int r = 0; r < 4; ++r)
                ldsRed[w][(rbase + r) * 16 + colW] = s4[r];
        }
        __syncthreads();

        float s = ldsRed[0][tid] + ldsRed[1][tid] + ldsRed[2][tid] + ldsRed[3][tid];
        int oidx = (nE * TT + t) * HH + jE;
        float hv = tanhf(out[oidx] + s);
        out[oidx] = hv;
        u32 hibits, lobits; split2(hv, hibits, lobits);
        int hidx = nE * HH + jE;
        nhi[hidx] = (u16)hibits;
        nlo[hidx] = (u16)lobits;

        group_barrier(cnt, gen, 64);   // h_t visible to whole group
    }
}

// ---------------------------------------------------------------------------
extern "C" void kernel_launch(void* const* d_in, const int* in_sizes, int n_in,
                              void* d_out, int out_size, void* d_ws, size_t ws_size,
                              hipStream_t stream) {
    const float* x  = (const float*)d_in[0];
    const float* h0 = (const float*)d_in[1];
    const float* Wx = (const float*)d_in[2];
    const float* Wh = (const float*)d_in[3];
    const float* b  = (const float*)d_in[4];
    float* out = (float*)d_out;

    char* ws = (char*)d_ws;
    u16* WxPh = (u16*)(ws);
    u16* WxPl = (u16*)(ws + (1u << 20));
    u16* WhPh = (u16*)(ws + (2u << 20));
    u16* WhPl = (u16*)(ws + (4u << 20));
    u16* hb   = (u16*)(ws + (6u << 20));              // [2][2][64][1024] = 512 KB
    u32* bar  = (u32*)(ws + (6u << 20) + (1u << 19)); // 4 groups x 64 uints

    hipMemsetAsync(bar, 0, 4 * 64 * sizeof(u32), stream);
    prep_kernel<<<2048, 256, 0, stream>>>(Wx, Wh, h0, WxPh, WxPl, WhPh, WhPl,
                                          hb, hb + NN * HH);
    rnn_kernel<<<256, 256, 0, stream>>>(x, b, WxPh, WxPl, WhPh, WhPl, hb, out, bar);
}

// Round 2
// 5202.275 us; speedup vs baseline: 2.0331x; 2.0331x over previous
//
#include <hip/hip_runtime.h>

// RNN: out[n,t,:] = tanh(x[n,t,:]@Wx + b + h_{t-1}@Wh),  h_{-1} = h0
// N=64, T=512, D=512, H=1024, fp32 in/out.
// Round 2: distributed-flag group barrier (no central atomic RMW chain),
// packed-u32 h with sc1 stores, phase-1 GEMM as separate kernel.

#define NN 64
#define TT 512
#define DD 512
#define HH 1024

typedef unsigned int  u32;
typedef unsigned short u16;

typedef __attribute__((ext_vector_type(8))) short bf16x8;
typedef __attribute__((ext_vector_type(4))) float f32x4;
typedef __attribute__((ext_vector_type(4))) u32   u32x4;

#define MFMA16(a, b, c) __builtin_amdgcn_mfma_f32_16x16x32_bf16((a), (b), (c), 0, 0, 0)

__device__ __forceinline__ u32 bf16r(float f) {          // RTNE fp32->bf16 (bits)
    u32 u = __float_as_uint(f);
    return (u + 0x7fffu + ((u >> 16) & 1u)) >> 16;
}
__device__ __forceinline__ float bf16tof(u32 h) { return __uint_as_float(h << 16); }
__device__ __forceinline__ void split2(float f, u32& hi, u32& lo) {
    hi = bf16r(f);
    lo = bf16r(f - bf16tof(hi));
}

// ---------------------------------------------------------------------------
// Prep: pack Wx and Wh into MFMA-fragment order (hi/lo bf16); pack h0 -> u32.
// Fragment layout for 16x16x32: elem index p = ((jt*KB + kb)*64 + lane)*8 + e
//   j = jt*16 + (lane&15),  k = kb*32 + (lane>>4)*8 + e
// ---------------------------------------------------------------------------
__global__ __launch_bounds__(256) void prep_kernel(
    const float* __restrict__ Wx, const float* __restrict__ Wh,
    const float* __restrict__ h0,
    u16* __restrict__ WxPh, u16* __restrict__ WxPl,
    u16* __restrict__ WhPh, u16* __restrict__ WhPl,
    u32* __restrict__ hpack0)
{
    const int stride = gridDim.x * 256;
    const int gid = blockIdx.x * 256 + threadIdx.x;

    // Wx: 64 jt x 16 kb x 64 lanes x 8 e = 524288
    for (int p = gid; p < 64 * 16 * 64 * 8; p += stride) {
        int e = p & 7, l = (p >> 3) & 63, kb = (p >> 9) & 15, jt = p >> 13;
        int j = jt * 16 + (l & 15);
        int k = kb * 32 + ((l >> 4) << 3) + e;
        u32 hi, lo; split2(Wx[k * HH + j], hi, lo);
        WxPh[p] = (u16)hi; WxPl[p] = (u16)lo;
    }
    // Wh: 64 jt x 32 kb x 64 lanes x 8 e = 1048576
    for (int p = gid; p < 64 * 32 * 64 * 8; p += stride) {
        int e = p & 7, l = (p >> 3) & 63, kb = (p >> 9) & 31, jt = p >> 14;
        int j = jt * 16 + (l & 15);
        int k = kb * 32 + ((l >> 4) << 3) + e;
        u32 hi, lo; split2(Wh[k * HH + j], hi, lo);
        WhPh[p] = (u16)hi; WhPl[p] = (u16)lo;
    }
    // h0 split -> packed parity-0 buffer
    for (int p = gid; p < NN * HH; p += stride) {
        u32 hi, lo; split2(h0[p], hi, lo);
        hpack0[p] = (hi << 16) | lo;
    }
}

// ---------------------------------------------------------------------------
// Phase 1: out = x@Wx + b   (split-bf16, 128x128 tiles, grid 2048)
// ---------------------------------------------------------------------------
__global__ __launch_bounds__(256) void gemm_kernel(
    const float* __restrict__ x, const float* __restrict__ b,
    const u16* __restrict__ WxPh, const u16* __restrict__ WxPl,
    float* __restrict__ out)
{
    __shared__ __align__(16) u32 ldsA[2][128][20];   // hi/lo x 128 rows x 32 bf16 (pad->40B rows)

    const int tid = threadIdx.x;
    const int bid = blockIdx.x;
    const int w   = tid >> 6;
    const int l   = tid & 63;
    const int wm = w >> 1, wj = w & 1;               // 64x64 wave tile in 128x128

    const int m0 = (bid >> 3) * 128;                 // row in [0,32768)
    const int jb = bid & 7;
    const int j0 = jb * 128;

    f32x4 acc[4][4] = {};
    for (int ks = 0; ks < 16; ++ks) {
        const int k0 = ks * 32;
        #pragma unroll
        for (int it = 0; it < 8; ++it) {
            int idx = it * 256 + tid;
            int m = idx >> 4, kp = idx & 15;
            float2 v = *(const float2*)(x + (m0 + m) * DD + k0 + kp * 2);
            u32 h0b, l0b, h1b, l1b;
            split2(v.x, h0b, l0b);
            split2(v.y, h1b, l1b);
            ldsA[0][m][kp] = h0b | (h1b << 16);
            ldsA[1][m][kp] = l0b | (l1b << 16);
        }
        __syncthreads();

        bf16x8 afh[4], afl[4], bfh[4], bfl[4];
        #pragma unroll
        for (int mt4 = 0; mt4 < 4; ++mt4) {
            int row = wm * 64 + mt4 * 16 + (l & 15);
            int co  = (l >> 4) * 4;
            afh[mt4] = *(const bf16x8*)&ldsA[0][row][co];
            afl[mt4] = *(const bf16x8*)&ldsA[1][row][co];
        }
        #pragma unroll
        for (int jt4 = 0; jt4 < 4; ++jt4) {
            int jtile = jb * 8 + wj * 4 + jt4;
            int off = ((jtile * 16 + ks) * 64 + l) * 8;
            bfh[jt4] = *(const bf16x8*)(WxPh + off);
            bfl[jt4] = *(const bf16x8*)(WxPl + off);
        }
        #pragma unroll
        for (int mt4 = 0; mt4 < 4; ++mt4)
            #pragma unroll
            for (int jt4 = 0; jt4 < 4; ++jt4) {
                acc[mt4][jt4] = MFMA16(afh[mt4], bfh[jt4], acc[mt4][jt4]);
                acc[mt4][jt4] = MFMA16(afh[mt4], bfl[jt4], acc[mt4][jt4]);
                acc[mt4][jt4] = MFMA16(afl[mt4], bfh[jt4], acc[mt4][jt4]);
            }
        __syncthreads();
    }
    #pragma unroll
    for (int jt4 = 0; jt4 < 4; ++jt4) {
        int j = j0 + wj * 64 + jt4 * 16 + (l & 15);
        float bj = b[j];
        #pragma unroll
        for (int mt4 = 0; mt4 < 4; ++mt4)
            #pragma unroll
            for (int r = 0; r < 4; ++r) {
                int m = m0 + wm * 64 + mt4 * 16 + (l >> 4) * 4 + r;
                out[m * HH + j] = acc[mt4][jt4][r] + bj;
            }
    }
}

// ---------------------------------------------------------------------------
// Phase 2: sequential scan. Grid 256 x 256. Group g = bid>>6 owns rows
// [16g,16g+16). Distributed-flag barrier: block wid sets flags[wid] = t+1
// (sc1), wave 0 polls all 64 flags in parallel, then agent-acquire fence.
// ---------------------------------------------------------------------------
__global__ __launch_bounds__(256, 1) void scan_kernel(
    const u16* __restrict__ WhPh, const u16* __restrict__ WhPl,
    u32* __restrict__ hb,            // [2 parity][64][1024] packed hi|lo
    float* __restrict__ out, u32* __restrict__ bar)
{
    __shared__ float ldsRed[4][256];

    const int tid = threadIdx.x;
    const int bid = blockIdx.x;
    const int g   = bid >> 6;       // batch group 0..3
    const int wid = bid & 63;       // block within group (= j-tile)
    const int w   = tid >> 6;       // wave 0..3
    const int l   = tid & 63;       // lane

    u32* flags = bar + g * 64 * 32;   // 64 flags, 128-B stride

    // this wave's Wh fragments: j in [wid*16,+16), k in [w*256,+256)
    bf16x8 Bh[8], Bl[8];
    #pragma unroll
    for (int i = 0; i < 8; ++i) {
        int off = ((wid * 32 + w * 8 + i) * 64 + l) * 8;
        Bh[i] = *(const bf16x8*)(WhPh + off);
        Bl[i] = *(const bf16x8*)(WhPl + off);
    }

    const int row16 = tid >> 4, col16 = tid & 15;
    const int nA = g * 16 + (l & 15);      // batch row of this lane's A-frag
    const int nE = g * 16 + row16;         // batch row this thread finalizes
    const int jE = wid * 16 + col16;
    const int kbase = w * 256 + ((l >> 4) << 3);

    float xw = out[(nE * TT + 0) * HH + jE];   // phase-1 value (kernel boundary = visible)

    for (int t = 0; t < TT; ++t) {
        const u32* hsrc = hb + (t & 1) * NN * HH + nA * HH + kbase;

        // prefetch next step's xw (only this thread ever writes that slot)
        float xw_n = 0.f;
        if (t + 1 < TT) xw_n = out[(nE * TT + t + 1) * HH + jE];

        bf16x8 Ah[8], Al[8];
        #pragma unroll
        for (int i = 0; i < 8; ++i) {
            u32x4 va = *(const u32x4*)(hsrc + i * 32);
            u32x4 vb = *(const u32x4*)(hsrc + i * 32 + 4);
            bf16x8 ah, al;
            ah[0] = (short)(va[0] >> 16); al[0] = (short)(va[0] & 0xffffu);
            ah[1] = (short)(va[1] >> 16); al[1] = (short)(va[1] & 0xffffu);
            ah[2] = (short)(va[2] >> 16); al[2] = (short)(va[2] & 0xffffu);
            ah[3] = (short)(va[3] >> 16); al[3] = (short)(va[3] & 0xffffu);
            ah[4] = (short)(vb[0] >> 16); al[4] = (short)(vb[0] & 0xffffu);
            ah[5] = (short)(vb[1] >> 16); al[5] = (short)(vb[1] & 0xffffu);
            ah[6] = (short)(vb[2] >> 16); al[6] = (short)(vb[2] & 0xffffu);
            ah[7] = (short)(vb[3] >> 16); al[7] = (short)(vb[3] & 0xffffu);
            Ah[i] = ah; Al[i] = al;
        }

        f32x4 ahh = {}, ahl = {}, alh = {};   // 3 independent chains
        #pragma unroll
        for (int i = 0; i < 8; ++i) {
            ahh = MFMA16(Ah[i], Bh[i], ahh);
            ahl = MFMA16(Ah[i], Bl[i], ahl);
            alh = MFMA16(Al[i], Bh[i], alh);
        }
        f32x4 s4 = ahh + ahl + alh;

        // cross-wave K reduction
        {
            int rbase = (l >> 4) * 4, colW = l & 15;
            #pragma unroll
            for (int r = 0; r < 4; ++r)
                ldsRed[w][(rbase + r) * 16 + colW] = s4[r];
        }
        __syncthreads();
        float s = ldsRed[0][tid] + ldsRed[1][tid] + ldsRed[2][tid] + ldsRed[3][tid];

        float hv = tanhf(xw + s);
        out[(nE * TT + t) * HH + jE] = hv;

        if (t + 1 < TT) {
            u32 hibits, lobits; split2(hv, hibits, lobits);
            __hip_atomic_store(hb + ((t & 1) ^ 1) * NN * HH + nE * HH + jE,
                               (hibits << 16) | lobits,
                               __ATOMIC_RELAXED, __HIP_MEMORY_SCOPE_AGENT);
            // make sure this wave's sc1 h-stores reached the coherence point
            asm volatile("s_waitcnt vmcnt(0)" ::: "memory");
            __syncthreads();                        // all waves done storing
            if (tid == 0)
                __hip_atomic_store(flags + wid * 32, (u32)(t + 1),
                                   __ATOMIC_RELAXED, __HIP_MEMORY_SCOPE_AGENT);
            if (w == 0) {
                const u32* f = flags + l * 32;      // lane l polls block l's flag
                while (__hip_atomic_load(f, __ATOMIC_RELAXED,
                                         __HIP_MEMORY_SCOPE_AGENT) < (u32)(t + 1)) {}
            }
            __syncthreads();
            __builtin_amdgcn_fence(__ATOMIC_ACQUIRE, "agent");  // drop stale L2 h lines
        }
        xw = xw_n;
    }
}

// ---------------------------------------------------------------------------
extern "C" void kernel_launch(void* const* d_in, const int* in_sizes, int n_in,
                              void* d_out, int out_size, void* d_ws, size_t ws_size,
                              hipStream_t stream) {
    const float* x  = (const float*)d_in[0];
    const float* h0 = (const float*)d_in[1];
    const float* Wx = (const float*)d_in[2];
    const float* Wh = (const float*)d_in[3];
    const float* b  = (const float*)d_in[4];
    float* out = (float*)d_out;

    char* ws = (char*)d_ws;
    u16* WxPh = (u16*)(ws);
    u16* WxPl = (u16*)(ws + (1u << 20));
    u16* WhPh = (u16*)(ws + (2u << 20));
    u16* WhPl = (u16*)(ws + (4u << 20));
    u32* hb   = (u32*)(ws + (6u << 20));              // [2][64][1024] u32 = 512 KB
    u32* bar  = (u32*)(ws + (6u << 20) + (1u << 19)); // 4 groups x 64 x 32 u32 = 32 KB

    hipMemsetAsync(bar, 0, 4 * 64 * 32 * sizeof(u32), stream);
    prep_kernel<<<2048, 256, 0, stream>>>(Wx, Wh, h0, WxPh, WxPl, WhPh, WhPl, hb);
    gemm_kernel<<<2048, 256, 0, stream>>>(x, b, WxPh, WxPl, out);
    scan_kernel<<<256, 256, 0, stream>>>(WhPh, WhPl, hb, out, bar);
}

// Round 4
// 2101.731 us; speedup vs baseline: 5.0324x; 2.4752x over previous
//
#include <hip/hip_runtime.h>

// RNN: out[n,t,:] = tanh(x[n,t,:]@Wx + b + h_{t-1}@Wh),  h_{-1} = h0
// N=64, T=512, D=512, H=1024, fp32 in/out.
// Round 4: agent/system-scope exchange only (no XCD-locality gambles).
// 8 groups x 32 blocks; split hi/lo h arrays (direct dwordx4 A-frag loads);
// wave-0 posts h + flag; per-wave producer-subset polling; no cache inv.

#define NN 64
#define TT 512
#define DD 512
#define HH 1024

typedef unsigned int  u32;
typedef unsigned short u16;

typedef __attribute__((ext_vector_type(8))) short bf16x8;
typedef __attribute__((ext_vector_type(4))) float f32x4;
typedef __attribute__((ext_vector_type(4))) u32   u32x4;

#define MFMA16(a, b, c) __builtin_amdgcn_mfma_f32_16x16x32_bf16((a), (b), (c), 0, 0, 0)

__device__ __forceinline__ u32 bf16r(float f) {          // RTNE fp32->bf16 (bits)
    u32 u = __float_as_uint(f);
    return (u + 0x7fffu + ((u >> 16) & 1u)) >> 16;
}
__device__ __forceinline__ float bf16tof(u32 h) { return __uint_as_float(h << 16); }
__device__ __forceinline__ void split2(float f, u32& hi, u32& lo) {
    hi = bf16r(f);
    lo = bf16r(f - bf16tof(hi));
}

// ---- system-scope (sc0 sc1) memory ops: bypass L1+L2, served at IC --------
__device__ __forceinline__ bf16x8 ld16_sys(const u16* p) {
    u32x4 v;
    asm volatile("global_load_dwordx4 %0, %1, off sc0 sc1" : "=v"(v) : "v"(p));
    return __builtin_bit_cast(bf16x8, v);
}
__device__ __forceinline__ void st16_sys(u16* p, u32x4 v) {
    asm volatile("global_store_dwordx4 %0, %1, off sc0 sc1" :: "v"(p), "v"(v) : "memory");
}
__device__ __forceinline__ u32 ld_flag(const u32* p) {
    u32 v;
    asm volatile("global_load_dword %0, %1, off sc0 sc1\n\ts_waitcnt vmcnt(0)"
                 : "=v"(v) : "v"(p) : "memory");
    return v;
}
__device__ __forceinline__ void st_flag(u32* p, u32 v) {
    asm volatile("global_store_dword %0, %1, off sc0 sc1" :: "v"(p), "v"(v) : "memory");
}

// ---------------------------------------------------------------------------
// Prep: pack Wx and Wh into MFMA-fragment order (hi/lo bf16); split h0.
// Fragment layout for 16x16x32: p = ((jt*KB + kb)*64 + lane)*8 + e
//   j = jt*16 + (lane&15),  k = kb*32 + (lane>>4)*8 + e
// ---------------------------------------------------------------------------
__global__ __launch_bounds__(256) void prep_kernel(
    const float* __restrict__ Wx, const float* __restrict__ Wh,
    const float* __restrict__ h0,
    u16* __restrict__ WxPh, u16* __restrict__ WxPl,
    u16* __restrict__ WhPh, u16* __restrict__ WhPl,
    u16* __restrict__ h0H,  u16* __restrict__ h0L)
{
    const int stride = gridDim.x * 256;
    const int gid = blockIdx.x * 256 + threadIdx.x;

    for (int p = gid; p < 64 * 16 * 64 * 8; p += stride) {   // Wx
        int e = p & 7, l = (p >> 3) & 63, kb = (p >> 9) & 15, jt = p >> 13;
        int j = jt * 16 + (l & 15);
        int k = kb * 32 + ((l >> 4) << 3) + e;
        u32 hi, lo; split2(Wx[k * HH + j], hi, lo);
        WxPh[p] = (u16)hi; WxPl[p] = (u16)lo;
    }
    for (int p = gid; p < 64 * 32 * 64 * 8; p += stride) {   // Wh
        int e = p & 7, l = (p >> 3) & 63, kb = (p >> 9) & 31, jt = p >> 14;
        int j = jt * 16 + (l & 15);
        int k = kb * 32 + ((l >> 4) << 3) + e;
        u32 hi, lo; split2(Wh[k * HH + j], hi, lo);
        WhPh[p] = (u16)hi; WhPl[p] = (u16)lo;
    }
    for (int p = gid; p < NN * HH; p += stride) {            // h0 -> parity 0
        u32 hi, lo; split2(h0[p], hi, lo);
        h0H[p] = (u16)hi; h0L[p] = (u16)lo;
    }
}

// ---------------------------------------------------------------------------
// Phase 1: out = x@Wx + b   (split-bf16, 128x128 tiles, grid 2048)
// ---------------------------------------------------------------------------
__global__ __launch_bounds__(256) void gemm_kernel(
    const float* __restrict__ x, const float* __restrict__ b,
    const u16* __restrict__ WxPh, const u16* __restrict__ WxPl,
    float* __restrict__ out)
{
    __shared__ __align__(16) u32 ldsA[2][128][20];

    const int tid = threadIdx.x;
    const int bid = blockIdx.x;
    const int w   = tid >> 6;
    const int l   = tid & 63;
    const int wm = w >> 1, wj = w & 1;

    const int m0 = (bid >> 3) * 128;
    const int jb = bid & 7;
    const int j0 = jb * 128;

    f32x4 acc[4][4] = {};
    for (int ks = 0; ks < 16; ++ks) {
        const int k0 = ks * 32;
        #pragma unroll
        for (int it = 0; it < 8; ++it) {
            int idx = it * 256 + tid;
            int m = idx >> 4, kp = idx & 15;
            float2 v = *(const float2*)(x + (m0 + m) * DD + k0 + kp * 2);
            u32 h0b, l0b, h1b, l1b;
            split2(v.x, h0b, l0b);
            split2(v.y, h1b, l1b);
            ldsA[0][m][kp] = h0b | (h1b << 16);
            ldsA[1][m][kp] = l0b | (l1b << 16);
        }
        __syncthreads();

        bf16x8 afh[4], afl[4], bfh[4], bfl[4];
        #pragma unroll
        for (int mt4 = 0; mt4 < 4; ++mt4) {
            int row = wm * 64 + mt4 * 16 + (l & 15);
            int co  = (l >> 4) * 4;
            afh[mt4] = *(const bf16x8*)&ldsA[0][row][co];
            afl[mt4] = *(const bf16x8*)&ldsA[1][row][co];
        }
        #pragma unroll
        for (int jt4 = 0; jt4 < 4; ++jt4) {
            int jtile = jb * 8 + wj * 4 + jt4;
            int off = ((jtile * 16 + ks) * 64 + l) * 8;
            bfh[jt4] = *(const bf16x8*)(WxPh + off);
            bfl[jt4] = *(const bf16x8*)(WxPl + off);
        }
        #pragma unroll
        for (int mt4 = 0; mt4 < 4; ++mt4)
            #pragma unroll
            for (int jt4 = 0; jt4 < 4; ++jt4) {
                acc[mt4][jt4] = MFMA16(afh[mt4], bfh[jt4], acc[mt4][jt4]);
                acc[mt4][jt4] = MFMA16(afh[mt4], bfl[jt4], acc[mt4][jt4]);
                acc[mt4][jt4] = MFMA16(afl[mt4], bfh[jt4], acc[mt4][jt4]);
            }
        __syncthreads();
    }
    #pragma unroll
    for (int jt4 = 0; jt4 < 4; ++jt4) {
        int j = j0 + wj * 64 + jt4 * 16 + (l & 15);
        float bj = b[j];
        #pragma unroll
        for (int mt4 = 0; mt4 < 4; ++mt4)
            #pragma unroll
            for (int r = 0; r < 4; ++r) {
                int m = m0 + wm * 64 + mt4 * 16 + (l >> 4) * 4 + r;
                out[m * HH + j] = acc[mt4][jt4][r] + bj;
            }
    }
}

// ---------------------------------------------------------------------------
// Phase 2: scan. Grid 256 x 256. Group g = bid&7 owns rows [8g,8g+8);
// block wid = bid>>3 owns cols [32wid,32wid+32); wave w owns k [256w,+256).
// Flags: flags[g*32+wid] = t+1 means "h_t from block wid is at the IC".
// Wave w of any block only needs producers 8w..8w+7 (its k-slice columns).
// ---------------------------------------------------------------------------
__global__ __launch_bounds__(256, 2) void scan_kernel(
    const u16* __restrict__ WhPh, const u16* __restrict__ WhPl,
    u16* __restrict__ hbH, u16* __restrict__ hbL,   // [2 parity][64][1024]
    float* __restrict__ out, u32* __restrict__ flags)
{
    __shared__ float ldsRed[4][8][32];
    __shared__ __align__(16) u16 ldsHh[8][32];
    __shared__ __align__(16) u16 ldsHl[8][32];

    const int tid = threadIdx.x;
    const int bid = blockIdx.x;
    const int g   = bid & 7;
    const int wid = bid >> 3;
    const int w   = tid >> 6;
    const int l   = tid & 63;

    // Wh fragments: j-tiles {2wid, 2wid+1}, k-slice [256w, 256w+256)
    bf16x8 Bh[2][8], Bl[2][8];
    #pragma unroll
    for (int jj = 0; jj < 2; ++jj)
        #pragma unroll
        for (int i = 0; i < 8; ++i) {
            int off = (((wid * 2 + jj) * 32 + w * 8 + i) * 64 + l) * 8;
            Bh[jj][i] = *(const bf16x8*)(WhPh + off);
            Bl[jj][i] = *(const bf16x8*)(WhPl + off);
        }

    const int r = tid >> 5, c = tid & 31;          // this thread's output elem
    const int nE = g * 8 + r, jE = wid * 32 + c;
    const int nA = g * 8 + (l & 7);                // A-frag batch row
    const int kbase = w * 256 + ((l >> 4) << 3);
    u32* gflags = flags + g * 32;

    float xw = out[(nE * TT) * HH + jE];

    for (int t = 0; t < TT; ++t) {
        const int par = t & 1;

        if (t > 0) {                               // wait for h_{t-1}
            const u32 tgt = (u32)t;
            while (true) {
                u32 fv = tgt;
                if (l < 8) fv = ld_flag(gflags + 8 * w + l);
                if (__ballot(fv >= tgt) == ~0ull) break;
            }
        }

        float xw_n = 0.f;
        if (t + 1 < TT) xw_n = out[(nE * TT + t + 1) * HH + jE];

        const u16* hH = hbH + par * NN * HH + nA * HH + kbase;
        const u16* hL = hbL + par * NN * HH + nA * HH + kbase;

        f32x4 ahh[2] = {}, ahl[2] = {}, alh[2] = {};
        #pragma unroll
        for (int half = 0; half < 2; ++half) {
            bf16x8 Ah[4], Al[4];
            #pragma unroll
            for (int i = 0; i < 4; ++i) {
                Ah[i] = ld16_sys(hH + (half * 4 + i) * 32);
                Al[i] = ld16_sys(hL + (half * 4 + i) * 32);
            }
            asm volatile("s_waitcnt vmcnt(0)" ::: "memory");
            __builtin_amdgcn_sched_barrier(0);
            #pragma unroll
            for (int i = 0; i < 4; ++i) {
                int fi = half * 4 + i;
                #pragma unroll
                for (int jj = 0; jj < 2; ++jj) {
                    ahh[jj] = MFMA16(Ah[i], Bh[jj][fi], ahh[jj]);
                    ahl[jj] = MFMA16(Ah[i], Bl[jj][fi], ahl[jj]);
                    alh[jj] = MFMA16(Al[i], Bh[jj][fi], alh[jj]);
                }
            }
        }

        // per-wave partials -> LDS (valid rows 0..7 live in lanes 0..31)
        {
            int rb = (l >> 4) * 4, cl = l & 15;
            if (rb < 8) {
                #pragma unroll
                for (int jj = 0; jj < 2; ++jj) {
                    f32x4 s4 = ahh[jj] + ahl[jj] + alh[jj];
                    #pragma unroll
                    for (int e = 0; e < 4; ++e)
                        ldsRed[w][rb + e][jj * 16 + cl] = s4[e];
                }
            }
        }
        __syncthreads();
        float s = ldsRed[0][r][c] + ldsRed[1][r][c] + ldsRed[2][r][c] + ldsRed[3][r][c];

        float hv = tanhf(xw + s);
        out[(nE * TT + t) * HH + jE] = hv;

        if (t + 1 < TT) {
            u32 hi, lo; split2(hv, hi, lo);
            ldsHh[r][c] = (u16)hi;
            ldsHl[r][c] = (u16)lo;
        }
        __syncthreads();

        if (t + 1 < TT && w == 0) {
            // lanes 0-31: hi halves; lanes 32-63: lo halves. 16B per lane.
            const int li = l & 31;
            const int rr = li >> 2, c8 = (li & 3) * 8;
            const u16* src = (l < 32) ? &ldsHh[rr][c8] : &ldsHl[rr][c8];
            u32x4 vv = *(const u32x4*)src;
            u16* dbase = (l < 32) ? hbH : hbL;
            u16* dst = dbase + (par ^ 1) * NN * HH + (g * 8 + rr) * HH + wid * 32 + c8;
            st16_sys(dst, vv);
            asm volatile("s_waitcnt vmcnt(0)" ::: "memory");   // acked at IC
            if (l == 0) st_flag(gflags + wid, (u32)(t + 1));
        }
        xw = xw_n;
    }
}

// ---------------------------------------------------------------------------
extern "C" void kernel_launch(void* const* d_in, const int* in_sizes, int n_in,
                              void* d_out, int out_size, void* d_ws, size_t ws_size,
                              hipStream_t stream) {
    const float* x  = (const float*)d_in[0];
    const float* h0 = (const float*)d_in[1];
    const float* Wx = (const float*)d_in[2];
    const float* Wh = (const float*)d_in[3];
    const float* b  = (const float*)d_in[4];
    float* out = (float*)d_out;

    char* ws = (char*)d_ws;
    u16* WxPh = (u16*)(ws);                           // 1 MB
    u16* WxPl = (u16*)(ws + (1u << 20));              // 1 MB
    u16* WhPh = (u16*)(ws + (2u << 20));              // 2 MB
    u16* WhPl = (u16*)(ws + (4u << 20));              // 2 MB
    u16* hbH  = (u16*)(ws + (6u << 20));              // [2][64][1024] u16 = 256 KB
    u16* hbL  = (u16*)(ws + (6u << 20) + (1u << 18)); // 256 KB
    u32* flags= (u32*)(ws + (6u << 20) + (1u << 19)); // 8 x 32 u32 = 1 KB

    hipMemsetAsync(flags, 0, 8 * 32 * sizeof(u32), stream);
    prep_kernel<<<2048, 256, 0, stream>>>(Wx, Wh, h0, WxPh, WxPl, WhPh, WhPl,
                                          hbH, hbL);
    gemm_kernel<<<2048, 256, 0, stream>>>(x, b, WxPh, WxPl, out);
    scan_kernel<<<256, 256, 0, stream>>>(WhPh, WhPl, hbH, hbL, out, flags);
}